// Round 1
// baseline (25676.834 us; speedup 1.0000x reference)
//
#include <hip/hip_runtime.h>
#include <hip/hip_bf16.h>
#include <cstddef>

// EdgeLevelRNN: B=1024, T=64, N=128, E=H=NH=256, HEADS=4, DH=64, F=1, L=2
//
// Strategy:
//  - Precompute (parallel GEMMs, bf16 MFMA 16x16x32):
//      PK1: k_all/v_all = phn @ [Wk;Wv]^T + bias     (131072 x 512, K=256) -> bf16
//      PK2: gi0_all = relu(x*W_in+b_in) @ Wih0^T + bih0 (65536 x 768, K=256) -> bf16
//      + 7 small f32->bf16 weight conversions into workspace.
//  - Sequential kernel: 256 blocks x 512 threads, each block owns 4 batch
//    elements for all 64 timesteps (recurrence is per-batch independent; no
//    grid sync). h-state + stage buffers in LDS (44 KB, aliased). All
//    recurrent GEMVs stream bf16 weights (8-lanes-per-row coalesced pattern),
//    f32 accumulate, f32 elementwise/state.
// Workspace: ~237 MB (bf16 weights + k/v + gi0). Fully rewritten every call.

#define B_  1024
#define T_  64
#define N_  128
#define H_  256

typedef __attribute__((ext_vector_type(8))) short s16x8;
typedef __attribute__((ext_vector_type(4))) float f32x4;

__device__ __forceinline__ unsigned short f2b(float f) {
  unsigned int u = __float_as_uint(f);
  u += 0x7FFFu + ((u >> 16) & 1u);          // RNE
  return (unsigned short)(u >> 16);
}
__device__ __forceinline__ float blo(unsigned int u){ return __uint_as_float(u << 16); }
__device__ __forceinline__ float bhi(unsigned int u){ return __uint_as_float(u & 0xFFFF0000u); }
__device__ __forceinline__ float b2f(unsigned short s){ return __uint_as_float(((unsigned int)s) << 16); }
__device__ __forceinline__ float sigmoidf_(float x){ return 1.0f / (1.0f + __expf(-x)); }
__device__ __forceinline__ float tanhf_(float x){
  float t = __expf(-2.0f * fabsf(x));
  float r = (1.0f - t) / (1.0f + t);
  return x >= 0.0f ? r : -r;
}

__global__ void cvt_bf16(const float* __restrict__ s, unsigned short* __restrict__ d, int n) {
  int i = blockIdx.x * blockDim.x + threadIdx.x;
  if (i < n) d[i] = f2b(s[i]);
}

#define LDA 264   // 256 + 8 pad (bf16 elems)
#define LDB 40    // 32 + 8 pad

// PK1: C[m, 0:512] = phn[m,:] @ [Wk;Wv]^T + [bk;bv]; split to k_all / v_all (bf16)
__global__ __launch_bounds__(256) void kv_gemm(
    const float* __restrict__ phn,
    const float* __restrict__ Wk, const float* __restrict__ Wv,
    const float* __restrict__ bk, const float* __restrict__ bv,
    unsigned short* __restrict__ k_all, unsigned short* __restrict__ v_all)
{
  __shared__ __align__(16) unsigned short Alds[64 * LDA];
  __shared__ __align__(16) unsigned short Blds[256 * LDB];
  const int tid = threadIdx.x;
  const int m0 = blockIdx.x * 64;
  const int n0 = blockIdx.y * 256;
  // stage A: 64 x 256 f32 -> bf16
  #pragma unroll
  for (int p = 0; p < 16; ++p) {
    int q = p * 256 + tid;
    int row = q >> 6, kq = q & 63;
    float4 f = *(const float4*)&phn[(size_t)(m0 + row) * 256 + (size_t)kq * 4];
    ushort4 h; h.x = f2b(f.x); h.y = f2b(f.y); h.z = f2b(f.z); h.w = f2b(f.w);
    *(ushort4*)&Alds[row * LDA + kq * 4] = h;
  }
  const int wave = tid >> 6, lane = tid & 63;
  const int lr = lane & 15, lk = (lane >> 4) * 8;
  f32x4 acc[16];
  #pragma unroll
  for (int t = 0; t < 16; ++t) {
    int j = n0 + t * 16 + lr;
    float bz = (j < 256) ? bk[j] : bv[j - 256];
    acc[t][0] = bz; acc[t][1] = bz; acc[t][2] = bz; acc[t][3] = bz;
  }
  for (int kc = 0; kc < 8; ++kc) {
    __syncthreads();
    #pragma unroll
    for (int p = 0; p < 8; ++p) {
      int j = p * 32 + (tid >> 3);
      int jg = n0 + j;
      const float* wrow = (jg < 256) ? &Wk[(size_t)jg * 256] : &Wv[(size_t)(jg - 256) * 256];
      float4 f = *(const float4*)&wrow[kc * 32 + (tid & 7) * 4];
      ushort4 h; h.x = f2b(f.x); h.y = f2b(f.y); h.z = f2b(f.z); h.w = f2b(f.w);
      *(ushort4*)&Blds[j * LDB + (tid & 7) * 4] = h;
    }
    __syncthreads();
    s16x8 a = *(const s16x8*)&Alds[(wave * 16 + lr) * LDA + kc * 32 + lk];
    #pragma unroll
    for (int t = 0; t < 16; ++t) {
      s16x8 b = *(const s16x8*)&Blds[(t * 16 + lr) * LDB + lk];
      acc[t] = __builtin_amdgcn_mfma_f32_16x16x32_bf16(a, b, acc[t], 0, 0, 0);
    }
  }
  const int rbase = m0 + wave * 16 + (lane >> 4) * 4;
  #pragma unroll
  for (int t = 0; t < 16; ++t) {
    int j = n0 + t * 16 + lr;
    #pragma unroll
    for (int i = 0; i < 4; ++i) {
      size_t m = (size_t)(rbase + i);
      unsigned short hv = f2b(acc[t][i]);
      if (j < 256) k_all[m * 256 + j] = hv;
      else         v_all[m * 256 + (j - 256)] = hv;
    }
  }
}

// PK2: gi0[m, f0:f0+256] = relu(x[m]*W_in + b_in) @ Wih0^T + bih0  (bf16 out)
__global__ __launch_bounds__(256) void gi0_gemm(
    const float* __restrict__ x, const float* __restrict__ W_in, const float* __restrict__ b_in,
    const float* __restrict__ Wih0, const float* __restrict__ bih0,
    unsigned short* __restrict__ gi0)
{
  __shared__ __align__(16) unsigned short Alds[64 * LDA];
  __shared__ __align__(16) unsigned short Blds[256 * LDB];
  const int tid = threadIdx.x;
  const int m0 = blockIdx.x * 64;
  const int f0 = blockIdx.y * 256;
  float win = W_in[tid], bin = b_in[tid];
  for (int p = 0; p < 64; ++p) {
    float e = fmaxf(fmaf(x[m0 + p], win, bin), 0.0f);
    Alds[p * LDA + tid] = f2b(e);
  }
  const int wave = tid >> 6, lane = tid & 63;
  const int lr = lane & 15, lk = (lane >> 4) * 8;
  f32x4 acc[16];
  #pragma unroll
  for (int t = 0; t < 16; ++t) {
    float bz = bih0[f0 + t * 16 + lr];
    acc[t][0] = bz; acc[t][1] = bz; acc[t][2] = bz; acc[t][3] = bz;
  }
  for (int kc = 0; kc < 8; ++kc) {
    __syncthreads();
    #pragma unroll
    for (int p = 0; p < 8; ++p) {
      int j = p * 32 + (tid >> 3);
      const float* wrow = &Wih0[(size_t)(f0 + j) * 256];
      float4 f = *(const float4*)&wrow[kc * 32 + (tid & 7) * 4];
      ushort4 h; h.x = f2b(f.x); h.y = f2b(f.y); h.z = f2b(f.z); h.w = f2b(f.w);
      *(ushort4*)&Blds[j * LDB + (tid & 7) * 4] = h;
    }
    __syncthreads();
    s16x8 a = *(const s16x8*)&Alds[(wave * 16 + lr) * LDA + kc * 32 + lk];
    #pragma unroll
    for (int t = 0; t < 16; ++t) {
      s16x8 b = *(const s16x8*)&Blds[(t * 16 + lr) * LDB + lk];
      acc[t] = __builtin_amdgcn_mfma_f32_16x16x32_bf16(a, b, acc[t], 0, 0, 0);
    }
  }
  const int rbase = m0 + wave * 16 + (lane >> 4) * 4;
  #pragma unroll
  for (int t = 0; t < 16; ++t) {
    int f = f0 + t * 16 + lr;
    #pragma unroll
    for (int i = 0; i < 4; ++i)
      gi0[(size_t)(rbase + i) * 768 + f] = f2b(acc[t][i]);
  }
}

// wave-cooperative GEMV over 4 batches: out[g][r] = act((sum_k in[g][k]*W[r][k]) + bias[r]) * scale
// 8 waves; each wave handles ROWS/8 rows, 16 rows per group (2 rows/lane, 8 lanes/row).
template<int K, int ROWS, int ACT>
__device__ __forceinline__ void gemv8(
    int wave, int lane,
    const float* __restrict__ inA, const float* __restrict__ inB,
    const unsigned short* __restrict__ W,
    const float* __restrict__ bias, float scale,
    float* __restrict__ outp, int ostride)
{
  constexpr int RPW  = ROWS / 8;
  constexpr int NGRP = RPW / 16;
  constexpr int NIT  = K / 64;
  const int lsub = lane & 7;
  const int rof  = lane >> 3;
  const int fbase = wave * RPW;
  #pragma unroll 1
  for (int grp = 0; grp < NGRP; ++grp) {
    const int r0 = fbase + grp * 16 + rof;
    const unsigned short* wp0 = W + (size_t)r0 * K;
    const unsigned short* wp1 = wp0 + (size_t)8 * K;
    uint4 WA[NIT], WB[NIT];
    #pragma unroll
    for (int it = 0; it < NIT; ++it) {
      WA[it] = *(const uint4*)(wp0 + lsub * 8 + it * 64);
      WB[it] = *(const uint4*)(wp1 + lsub * 8 + it * 64);
    }
    float acc0[4] = {0.f, 0.f, 0.f, 0.f}, acc1[4] = {0.f, 0.f, 0.f, 0.f};
    #pragma unroll
    for (int it = 0; it < NIT; ++it) {
      const int kk = lsub * 8 + it * 64;
      const float* src; int koff;
      if (K == 512) { src = (kk >= 256) ? inB : inA; koff = kk & 255; }
      else          { src = inA; koff = kk; }
      uint4 wa = WA[it], wb = WB[it];
      float wv0[8] = {blo(wa.x), bhi(wa.x), blo(wa.y), bhi(wa.y),
                      blo(wa.z), bhi(wa.z), blo(wa.w), bhi(wa.w)};
      float wv1[8] = {blo(wb.x), bhi(wb.x), blo(wb.y), bhi(wb.y),
                      blo(wb.z), bhi(wb.z), blo(wb.w), bhi(wb.w)};
      #pragma unroll
      for (int g = 0; g < 4; ++g) {
        float4 xa = *(const float4*)(src + g * 256 + koff);
        float4 xb = *(const float4*)(src + g * 256 + koff + 4);
        float xs[8] = {xa.x, xa.y, xa.z, xa.w, xb.x, xb.y, xb.z, xb.w};
        #pragma unroll
        for (int j = 0; j < 8; ++j) {
          acc0[g] = fmaf(wv0[j], xs[j], acc0[g]);
          acc1[g] = fmaf(wv1[j], xs[j], acc1[g]);
        }
      }
    }
    #pragma unroll
    for (int g = 0; g < 4; ++g) {
      float v0 = acc0[g], v1 = acc1[g];
      v0 += __shfl_xor(v0, 1); v0 += __shfl_xor(v0, 2); v0 += __shfl_xor(v0, 4);
      v1 += __shfl_xor(v1, 1); v1 += __shfl_xor(v1, 2); v1 += __shfl_xor(v1, 4);
      if (lsub == 0) {
        float o0 = v0 + bias[r0];
        float o1 = v1 + bias[r0 + 8];
        if (ACT == 1) { o0 = fmaxf(o0, 0.f); o1 = fmaxf(o1, 0.f); }
        outp[g * ostride + r0]     = o0 * scale;
        outp[g * ostride + r0 + 8] = o1 * scale;
      }
    }
  }
}

__global__ __launch_bounds__(512) void seq_kernel(
    const unsigned short* __restrict__ gi0,
    const unsigned short* __restrict__ k_all,
    const unsigned short* __restrict__ v_all,
    const float* __restrict__ h0_init,
    const unsigned short* __restrict__ w_hh0, const float* __restrict__ bhh0,
    const unsigned short* __restrict__ w_ih1, const float* __restrict__ bih1,
    const unsigned short* __restrict__ w_hh1, const float* __restrict__ bhh1,
    const unsigned short* __restrict__ w_q,  const float* __restrict__ bq,
    const unsigned short* __restrict__ w_o,  const float* __restrict__ bo,
    const unsigned short* __restrict__ w_c,  const float* __restrict__ bc,
    const unsigned short* __restrict__ w_1,  const float* __restrict__ b1,
    const float* __restrict__ W2, const float* __restrict__ b2,
    const unsigned char* __restrict__ amask,
    float* __restrict__ out)
{
  __shared__ __align__(16) float smem[11264];   // 44 KB, buffers aliased by lifetime
  float* h0s = smem;             // [4][256]
  float* h1s = smem + 1024;      // [4][256]
  float* gA  = smem + 2048;      // [4][768]  (gh0)
  float* gB  = smem + 5120;      // [4][768]  (gi1)
  float* gC  = smem + 8192;      // [4][768]  (gh1)
  float* qs    = gA;             // [4][256]  after GRU0, gA region is free
  float* sc    = gA + 1024;      // [16][128] scores -> softmax probs
  float* w1s   = gB;             // [4][256]  after GRU1, gB region is free
  float* ctxs  = gC;             // [4][256]  after GRU1, gC region is free
  float* os    = gC + 1024;      // [4][256]
  float* combs = gC + 2048;      // [4][256]

  const int tid = threadIdx.x;
  const int wave = tid >> 6, lane = tid & 63;
  const int b0 = blockIdx.x * 4;

  for (int i = tid; i < 1024; i += 512) {
    int g = i >> 8, f = i & 255;
    h0s[i] = h0_init[(size_t)(b0 + g) * 256 + f];
    h1s[i] = h0_init[(size_t)(B_ * H_) + (size_t)(b0 + g) * 256 + f];
  }
  __syncthreads();

  for (int t = 0; t < T_; ++t) {
    // S1: gh0 = h0 @ Whh0^T + bhh0
    gemv8<256, 768, 0>(wave, lane, h0s, nullptr, w_hh0, bhh0, 1.0f, gA, 768);
    __syncthreads();
    // GRU0 elementwise -> h0s
    #pragma unroll
    for (int i = 0; i < 2; ++i) {
      int idx = tid + i * 512;
      int g = idx >> 8, f = idx & 255;
      const unsigned short* gi = gi0 + ((size_t)(b0 + g) * T_ + t) * 768;
      float ir = b2f(gi[f]), iz = b2f(gi[256 + f]), inn = b2f(gi[512 + f]);
      float r = sigmoidf_(ir + gA[g * 768 + f]);
      float z = sigmoidf_(iz + gA[g * 768 + 256 + f]);
      float n = tanhf_(inn + r * gA[g * 768 + 512 + f]);
      h0s[idx] = (1.0f - z) * n + z * h0s[idx];
    }
    __syncthreads();
    // S2: gi1 = h0n @ Wih1^T + bih1 ; gh1 = h1 @ Whh1^T + bhh1
    gemv8<256, 768, 0>(wave, lane, h0s, nullptr, w_ih1, bih1, 1.0f, gB, 768);
    gemv8<256, 768, 0>(wave, lane, h1s, nullptr, w_hh1, bhh1, 1.0f, gC, 768);
    __syncthreads();
    // GRU1 elementwise -> h1s
    #pragma unroll
    for (int i = 0; i < 2; ++i) {
      int idx = tid + i * 512;
      int g = idx >> 8, f = idx & 255;
      float r = sigmoidf_(gB[g * 768 + f] + gC[g * 768 + f]);
      float z = sigmoidf_(gB[g * 768 + 256 + f] + gC[g * 768 + 256 + f]);
      float n = tanhf_(gB[g * 768 + 512 + f] + r * gC[g * 768 + 512 + f]);
      h1s[idx] = (1.0f - z) * n + z * h1s[idx];
    }
    __syncthreads();
    // S3: q = (h1n @ Wq^T + bq) * 0.125
    gemv8<256, 256, 0>(wave, lane, h1s, nullptr, w_q, bq, 0.125f, qs, 256);
    __syncthreads();
    // S4: scores[g][h][n] = q[g,h,:] . k[b][n][h,:]  (+mask)
    {
      int g = wave >> 1;
      const unsigned short* kb = k_all + (size_t)(b0 + g) * N_ * 256;
      int nsub = lane >> 3, dsub = lane & 7;
      #pragma unroll
      for (int hh = 0; hh < 2; ++hh) {
        int h = (wave & 1) * 2 + hh;
        const float* qrow = qs + g * 256 + h * 64;
        float4 qa = *(const float4*)(qrow + dsub * 8);
        float4 qb = *(const float4*)(qrow + dsub * 8 + 4);
        for (int nb = 0; nb < 16; ++nb) {
          int n = nb * 8 + nsub;
          uint4 kv = *(const uint4*)(kb + (size_t)n * 256 + h * 64 + dsub * 8);
          float a = blo(kv.x) * qa.x + bhi(kv.x) * qa.y + blo(kv.y) * qa.z + bhi(kv.y) * qa.w
                  + blo(kv.z) * qb.x + bhi(kv.z) * qb.y + blo(kv.w) * qb.z + bhi(kv.w) * qb.w;
          a += __shfl_xor(a, 1); a += __shfl_xor(a, 2); a += __shfl_xor(a, 4);
          if (dsub == 0) {
            float sv = amask[(size_t)(b0 + g) * N_ + n] ? -1e9f : a;
            sc[(g * 4 + h) * 128 + n] = sv;
          }
        }
      }
    }
    __syncthreads();
    // softmax over n (16 rows x 128)
    {
      int row = tid >> 5, c = tid & 31;
      float* srow = sc + row * 128;
      float4 v = *(const float4*)(srow + c * 4);
      float mx = fmaxf(fmaxf(v.x, v.y), fmaxf(v.z, v.w));
      #pragma unroll
      for (int mm = 1; mm <= 16; mm <<= 1) mx = fmaxf(mx, __shfl_xor(mx, mm));
      float e0 = __expf(v.x - mx), e1 = __expf(v.y - mx);
      float e2 = __expf(v.z - mx), e3 = __expf(v.w - mx);
      float s = e0 + e1 + e2 + e3;
      #pragma unroll
      for (int mm = 1; mm <= 16; mm <<= 1) s += __shfl_xor(s, mm);
      float inv = 1.0f / s;
      float4 o; o.x = e0 * inv; o.y = e1 * inv; o.z = e2 * inv; o.w = e3 * inv;
      *(float4*)(srow + c * 4) = o;
    }
    __syncthreads();
    // S5: ctx[g][j] = sum_n a[g][h][n] * v[b][n][j]
    #pragma unroll
    for (int i = 0; i < 2; ++i) {
      int idx = tid + i * 512;
      int g = idx >> 8, j = idx & 255, h = j >> 6;
      const unsigned short* vb = v_all + (size_t)(b0 + g) * N_ * 256 + j;
      const float* arow = sc + (g * 4 + h) * 128;
      float acc = 0.f;
      #pragma unroll 8
      for (int n = 0; n < N_; ++n)
        acc = fmaf(arow[n], b2f(vb[(size_t)n * 256]), acc);
      ctxs[g * 256 + j] = acc;
    }
    __syncthreads();
    // S6: o = ctx @ Wo^T + bo
    gemv8<256, 256, 0>(wave, lane, ctxs, nullptr, w_o, bo, 1.0f, os, 256);
    __syncthreads();
    // S7: comb = relu([h1n, o] @ Wc^T + bc)
    gemv8<512, 256, 1>(wave, lane, h1s, os, w_c, bc, 1.0f, combs, 256);
    __syncthreads();
    // S8: w1out = relu(comb @ W1^T + b1)
    gemv8<256, 256, 1>(wave, lane, combs, nullptr, w_1, b1, 1.0f, w1s, 256);
    __syncthreads();
    // S9: logit + sigmoid
    if (wave < 4) {
      int g = wave;
      float4 wv = *(const float4*)(W2 + lane * 4);
      float4 xv = *(const float4*)(w1s + g * 256 + lane * 4);
      float acc = wv.x * xv.x + wv.y * xv.y + wv.z * xv.z + wv.w * xv.w;
      #pragma unroll
      for (int mm = 1; mm <= 32; mm <<= 1) acc += __shfl_xor(acc, mm);
      if (lane == 0)
        out[(size_t)(b0 + g) * T_ + t] = sigmoidf_(acc + b2[0]);
    }
    __syncthreads();
  }
}

extern "C" void kernel_launch(void* const* d_in, const int* in_sizes, int n_in,
                              void* d_out, int out_size, void* d_ws, size_t ws_size,
                              hipStream_t stream)
{
  (void)in_sizes; (void)n_in; (void)out_size;
  const float* x    = (const float*)d_in[0];
  const float* phn  = (const float*)d_in[1];
  const float* h0i  = (const float*)d_in[2];
  const float* W_in = (const float*)d_in[3];
  const float* b_in = (const float*)d_in[4];
  const float* Wih0 = (const float*)d_in[5];
  const float* Whh0 = (const float*)d_in[6];
  const float* bih0 = (const float*)d_in[7];
  const float* bhh0 = (const float*)d_in[8];
  const float* Wih1 = (const float*)d_in[9];
  const float* Whh1 = (const float*)d_in[10];
  const float* bih1 = (const float*)d_in[11];
  const float* bhh1 = (const float*)d_in[12];
  const float* Wq = (const float*)d_in[13];
  const float* Wk = (const float*)d_in[14];
  const float* Wv = (const float*)d_in[15];
  const float* bq = (const float*)d_in[16];
  const float* bk = (const float*)d_in[17];
  const float* bv = (const float*)d_in[18];
  const float* Wo = (const float*)d_in[19];
  const float* bo = (const float*)d_in[20];
  const float* Wc = (const float*)d_in[21];
  const float* bc = (const float*)d_in[22];
  const float* W1 = (const float*)d_in[23];
  const float* b1 = (const float*)d_in[24];
  const float* W2 = (const float*)d_in[25];
  const float* b2 = (const float*)d_in[26];
  const unsigned char* amask = (const unsigned char*)d_in[27]; // jnp bool = 1 byte (all-false in test)
  float* out = (float*)d_out;

  // workspace layout (ushort units)
  unsigned short* ws = (unsigned short*)d_ws;
  size_t off = 0;
  unsigned short* w_hh0 = ws + off; off += 196608;
  unsigned short* w_ih1 = ws + off; off += 196608;
  unsigned short* w_hh1 = ws + off; off += 196608;
  unsigned short* w_q   = ws + off; off += 65536;
  unsigned short* w_o   = ws + off; off += 65536;
  unsigned short* w_c   = ws + off; off += 131072;
  unsigned short* w_1   = ws + off; off += 65536;
  unsigned short* k_all = ws + off; off += (size_t)B_ * N_ * 256;
  unsigned short* v_all = ws + off; off += (size_t)B_ * N_ * 256;
  unsigned short* gi0   = ws + off; off += (size_t)B_ * T_ * 768;
  if (ws_size < off * sizeof(unsigned short)) return;  // clean fail if ws too small

  hipLaunchKernelGGL(cvt_bf16, dim3((196608 + 511) / 512), dim3(512), 0, stream, Whh0, w_hh0, 196608);
  hipLaunchKernelGGL(cvt_bf16, dim3((196608 + 511) / 512), dim3(512), 0, stream, Wih1, w_ih1, 196608);
  hipLaunchKernelGGL(cvt_bf16, dim3((196608 + 511) / 512), dim3(512), 0, stream, Whh1, w_hh1, 196608);
  hipLaunchKernelGGL(cvt_bf16, dim3((65536 + 511) / 512), dim3(512), 0, stream, Wq, w_q, 65536);
  hipLaunchKernelGGL(cvt_bf16, dim3((65536 + 511) / 512), dim3(512), 0, stream, Wo, w_o, 65536);
  hipLaunchKernelGGL(cvt_bf16, dim3((131072 + 511) / 512), dim3(512), 0, stream, Wc, w_c, 131072);
  hipLaunchKernelGGL(cvt_bf16, dim3((65536 + 511) / 512), dim3(512), 0, stream, W1, w_1, 65536);

  hipLaunchKernelGGL(kv_gemm, dim3(2048, 2), dim3(256), 0, stream,
                     phn, Wk, Wv, bk, bv, k_all, v_all);
  hipLaunchKernelGGL(gi0_gemm, dim3(1024, 3), dim3(256), 0, stream,
                     x, W_in, b_in, Wih0, bih0, gi0);
  hipLaunchKernelGGL(seq_kernel, dim3(256), dim3(512), 0, stream,
                     gi0, k_all, v_all, h0i,
                     w_hh0, bhh0, w_ih1, bih1, w_hh1, bhh1,
                     w_q, bq, w_o, bo, w_c, bc, w_1, b1, W2, b2,
                     amask, out);
}

// Round 2
// 4511.860 us; speedup vs baseline: 5.6910x; 5.6910x over previous
//
#include <hip/hip_runtime.h>
#include <hip/hip_bf16.h>
#include <cstddef>
#include <cstdint>

// EdgeLevelRNN: B=1024, T=64, N=128, E=H=NH=256, HEADS=4, DH=64, F=1, L=2
// Phase A (parallel): k/v proj, gi0 = emb@Wih0^T (+bias), weight bf16 converts.
// Phase B (serial, 64 steps): ONLY the GRU recurrence. 256 blocks x 512 thr.
//   Per step: S1 = h0@Whh0^T -> fused GRU0 in D-frags; S2 = h0n@Wih1^T and
//   h1@Whh1^T -> fused GRU1. Weights stream L2->LDS via global_load_lds
//   (depth-4 pipeline, vmcnt(3)), MFMA 16x16x32 bf16, 2 barriers/step.
//   h1(t) stored to global for Phase C.
// Phase C (parallel over 65536 rows): q GEMM, attention per (b,head), fused
//   Wo/Wc/W1/W2 output chain.

#define B_  1024
#define T_  64
#define N_  128

typedef __attribute__((ext_vector_type(8))) short s16x8;
typedef __attribute__((ext_vector_type(4))) float f32x4;

__device__ __forceinline__ unsigned short f2b(float f) {
  unsigned int u = __float_as_uint(f);
  u += 0x7FFFu + ((u >> 16) & 1u);          // RNE
  return (unsigned short)(u >> 16);
}
__device__ __forceinline__ float b2f(unsigned short s){ return __uint_as_float(((unsigned int)s) << 16); }
__device__ __forceinline__ float sigmoidf_(float x){ return 1.0f / (1.0f + __expf(-x)); }
__device__ __forceinline__ float tanhf_(float x){
  float t = __expf(-2.0f * fabsf(x));
  float r = (1.0f - t) / (1.0f + t);
  return x >= 0.0f ? r : -r;
}
__device__ __forceinline__ void gld_lds16(const void* g, void* l) {
  __builtin_amdgcn_global_load_lds(
      (const __attribute__((address_space(1))) void*)g,
      (__attribute__((address_space(3))) void*)l, 16, 0, 0);
}
#define WAITV3 asm volatile("s_waitcnt vmcnt(3)" ::: "memory")
#define WAITV0 asm volatile("s_waitcnt vmcnt(0)" ::: "memory")

__global__ void cvt_bf16(const float* __restrict__ s, unsigned short* __restrict__ d, int n) {
  int i = blockIdx.x * blockDim.x + threadIdx.x;
  if (i < n) d[i] = f2b(s[i]);
}

#define LDA 264   // 256 + 8 pad (bf16 elems)
#define LDB 40    // 32 + 8 pad

// PK1: C[m, 0:512] = phn[m,:] @ [Wk;Wv]^T + [bk;bv]; split to k_all / v_all (bf16)
__global__ __launch_bounds__(256) void kv_gemm(
    const float* __restrict__ phn,
    const float* __restrict__ Wk, const float* __restrict__ Wv,
    const float* __restrict__ bk, const float* __restrict__ bv,
    unsigned short* __restrict__ k_all, unsigned short* __restrict__ v_all)
{
  __shared__ __align__(16) unsigned short Alds[64 * LDA];
  __shared__ __align__(16) unsigned short Blds[256 * LDB];
  const int tid = threadIdx.x;
  const int m0 = blockIdx.x * 64;
  const int n0 = blockIdx.y * 256;
  #pragma unroll
  for (int p = 0; p < 16; ++p) {
    int q = p * 256 + tid;
    int row = q >> 6, kq = q & 63;
    float4 f = *(const float4*)&phn[(size_t)(m0 + row) * 256 + (size_t)kq * 4];
    ushort4 h; h.x = f2b(f.x); h.y = f2b(f.y); h.z = f2b(f.z); h.w = f2b(f.w);
    *(ushort4*)&Alds[row * LDA + kq * 4] = h;
  }
  const int wave = tid >> 6, lane = tid & 63;
  const int lr = lane & 15, lk = (lane >> 4) * 8;
  f32x4 acc[16];
  #pragma unroll
  for (int t = 0; t < 16; ++t) {
    int j = n0 + t * 16 + lr;
    float bz = (j < 256) ? bk[j] : bv[j - 256];
    acc[t][0] = bz; acc[t][1] = bz; acc[t][2] = bz; acc[t][3] = bz;
  }
  for (int kc = 0; kc < 8; ++kc) {
    __syncthreads();
    #pragma unroll
    for (int p = 0; p < 8; ++p) {
      int j = p * 32 + (tid >> 3);
      int jg = n0 + j;
      const float* wrow = (jg < 256) ? &Wk[(size_t)jg * 256] : &Wv[(size_t)(jg - 256) * 256];
      float4 f = *(const float4*)&wrow[kc * 32 + (tid & 7) * 4];
      ushort4 h; h.x = f2b(f.x); h.y = f2b(f.y); h.z = f2b(f.z); h.w = f2b(f.w);
      *(ushort4*)&Blds[j * LDB + (tid & 7) * 4] = h;
    }
    __syncthreads();
    s16x8 a = *(const s16x8*)&Alds[(wave * 16 + lr) * LDA + kc * 32 + lk];
    #pragma unroll
    for (int t = 0; t < 16; ++t) {
      s16x8 b = *(const s16x8*)&Blds[(t * 16 + lr) * LDB + lk];
      acc[t] = __builtin_amdgcn_mfma_f32_16x16x32_bf16(a, b, acc[t], 0, 0, 0);
    }
  }
  const int rbase = m0 + wave * 16 + (lane >> 4) * 4;
  #pragma unroll
  for (int t = 0; t < 16; ++t) {
    int j = n0 + t * 16 + lr;
    #pragma unroll
    for (int i = 0; i < 4; ++i) {
      size_t m = (size_t)(rbase + i);
      unsigned short hv = f2b(acc[t][i]);
      if (j < 256) k_all[m * 256 + j] = hv;
      else         v_all[m * 256 + (j - 256)] = hv;
    }
  }
}

// PK2: gi0[t][b][f0:f0+256] = relu(x[m]*W_in + b_in) @ Wih0^T + bih0 (bf16)
__global__ __launch_bounds__(256) void gi0_gemm(
    const float* __restrict__ x, const float* __restrict__ W_in, const float* __restrict__ b_in,
    const float* __restrict__ Wih0, const float* __restrict__ bih0,
    unsigned short* __restrict__ gi0)
{
  __shared__ __align__(16) unsigned short Alds[64 * LDA];
  __shared__ __align__(16) unsigned short Blds[256 * LDB];
  const int tid = threadIdx.x;
  const int m0 = blockIdx.x * 64;
  const int f0 = blockIdx.y * 256;
  float win = W_in[tid], bin = b_in[tid];
  for (int p = 0; p < 64; ++p) {
    float e = fmaxf(fmaf(x[m0 + p], win, bin), 0.0f);
    Alds[p * LDA + tid] = f2b(e);
  }
  const int wave = tid >> 6, lane = tid & 63;
  const int lr = lane & 15, lk = (lane >> 4) * 8;
  f32x4 acc[16];
  #pragma unroll
  for (int t = 0; t < 16; ++t) {
    float bz = bih0[f0 + t * 16 + lr];
    acc[t][0] = bz; acc[t][1] = bz; acc[t][2] = bz; acc[t][3] = bz;
  }
  for (int kc = 0; kc < 8; ++kc) {
    __syncthreads();
    #pragma unroll
    for (int p = 0; p < 8; ++p) {
      int j = p * 32 + (tid >> 3);
      const float* wrow = &Wih0[(size_t)(f0 + j) * 256];
      float4 f = *(const float4*)&wrow[kc * 32 + (tid & 7) * 4];
      ushort4 h; h.x = f2b(f.x); h.y = f2b(f.y); h.z = f2b(f.z); h.w = f2b(f.w);
      *(ushort4*)&Blds[j * LDB + (tid & 7) * 4] = h;
    }
    __syncthreads();
    s16x8 a = *(const s16x8*)&Alds[(wave * 16 + lr) * LDA + kc * 32 + lk];
    #pragma unroll
    for (int t = 0; t < 16; ++t) {
      s16x8 b = *(const s16x8*)&Blds[(t * 16 + lr) * LDB + lk];
      acc[t] = __builtin_amdgcn_mfma_f32_16x16x32_bf16(a, b, acc[t], 0, 0, 0);
    }
  }
  const int rbase = m0 + wave * 16 + (lane >> 4) * 4;
  #pragma unroll
  for (int t = 0; t < 16; ++t) {
    int f = f0 + t * 16 + lr;
    #pragma unroll
    for (int i = 0; i < 4; ++i) {
      int m = rbase + i;                       // m = b*64 + t
      gi0[((size_t)(m & 63) * 1024 + (m >> 6)) * 768 + f] = f2b(acc[t][i]);
    }
  }
}

// ---------------- Phase B: minimal sequential GRU core ----------------
__global__ __launch_bounds__(512) void seq2_kernel(
    const unsigned short* __restrict__ gi0,     // [T][B][768]
    const float* __restrict__ h0_init,          // [2][B][256]
    const unsigned short* __restrict__ w_hh0, const float* __restrict__ bhh0,
    const unsigned short* __restrict__ w_ih1, const float* __restrict__ bih1,
    const unsigned short* __restrict__ w_hh1, const float* __restrict__ bhh1,
    unsigned short* __restrict__ h1_all)        // [B][T][256]
{
  __shared__ __align__(16) unsigned short wbuf[8][8][512];  // wave x 8 bufs x 1KB
  __shared__ __align__(16) float h0f[4][256];
  __shared__ __align__(16) float h1f[4][256];
  __shared__ __align__(16) unsigned short h0b[4][264];
  __shared__ __align__(16) unsigned short h1b[4][264];

  const int tid = threadIdx.x;
  const int w = tid >> 6, lane = tid & 63;
  const int col = lane & 15, kg = lane >> 4;
  const int b0 = blockIdx.x * 4;

  for (int i = tid; i < 1024; i += 512) {
    int g = i >> 8, f = i & 255;
    float v0 = h0_init[(size_t)(b0 + g) * 256 + f];
    float v1 = h0_init[(size_t)(B_ * 256) + (size_t)(b0 + g) * 256 + f];
    h0f[g][f] = v0; h1f[g][f] = v1;
    h0b[g][f] = f2b(v0); h1b[g][f] = f2b(v1);
  }
  __syncthreads();

  // per-lane weight offsets (ushort units): off6[j], j = gate*2+sub
  unsigned int off6[6];
  #pragma unroll
  for (int j = 0; j < 6; ++j) {
    int r0 = (j >> 1) * 256 + w * 32 + (j & 1) * 16;
    off6[j] = (unsigned)((r0 + col) * 256 + kg * 8);
  }
  // per-lane biases for this lane's f-columns
  float bb0[6], bb1[12];
  #pragma unroll
  for (int j = 0; j < 6; ++j) {
    int f = (j >> 1) * 256 + w * 32 + (j & 1) * 16 + col;
    bb0[j] = bhh0[f];
    bb1[j] = bih1[f];
    bb1[6 + j] = bhh1[f];
  }

  #pragma unroll 1
  for (int t = 0; t < T_; ++t) {
    // ---- S1: gh0 = h0 @ Whh0^T + bhh0, fused GRU0 ----
    f32x4 acc[6];
    #pragma unroll
    for (int j = 0; j < 6; ++j) { float bz = bb0[j]; acc[j][0]=bz; acc[j][1]=bz; acc[j][2]=bz; acc[j][3]=bz; }
    #pragma unroll
    for (int kc = 0; kc < 4; ++kc)
      gld_lds16(w_hh0 + off6[0] + kc * 32, &wbuf[w][kc][0]);
    #pragma unroll
    for (int j = 0; j < 6; ++j) {
      #pragma unroll
      for (int kc = 0; kc < 8; ++kc) {
        const int g = j * 8 + kc;
        if (g < 44) { WAITV3; } else if (g == 44) { WAITV0; }
        s16x8 bf_ = *(const s16x8*)&wbuf[w][g & 7][(size_t)lane * 8];
        s16x8 af_ = *(const s16x8*)&h0b[col & 3][kc * 32 + kg * 8];
        acc[j] = __builtin_amdgcn_mfma_f32_16x16x32_bf16(af_, bf_, acc[j], 0, 0, 0);
        if (g + 4 < 48) {
          const int gn = g + 4, jn = gn >> 3, kn = gn & 7;
          gld_lds16(w_hh0 + off6[jn] + kn * 32, &wbuf[w][gn & 7][0]);
        }
      }
    }
    if (lane < 16) {
      const size_t gbase = ((size_t)t * 1024 + b0) * 768;
      #pragma unroll
      for (int i = 0; i < 4; ++i) {
        const unsigned short* gp = gi0 + gbase + (size_t)i * 768;
        #pragma unroll
        for (int sub = 0; sub < 2; ++sub) {
          int f = w * 32 + sub * 16 + col;
          float ir = b2f(gp[f]), iz = b2f(gp[256 + f]), in_ = b2f(gp[512 + f]);
          float r = sigmoidf_(ir + acc[sub][i]);
          float z = sigmoidf_(iz + acc[2 + sub][i]);
          float n = tanhf_(in_ + r * acc[4 + sub][i]);
          float hn = (1.0f - z) * n + z * h0f[i][f];
          h0f[i][f] = hn;
          h0b[i][f] = f2b(hn);
        }
      }
    }
    __syncthreads();

    // ---- S2: gi1 = h0n @ Wih1^T + bih1 ; gh1 = h1 @ Whh1^T + bhh1, fused GRU1 ----
    f32x4 acc2[12];
    #pragma unroll
    for (int j = 0; j < 12; ++j) { float bz = bb1[j]; acc2[j][0]=bz; acc2[j][1]=bz; acc2[j][2]=bz; acc2[j][3]=bz; }
    #pragma unroll
    for (int kc = 0; kc < 4; ++kc)
      gld_lds16(w_ih1 + off6[0] + kc * 32, &wbuf[w][kc][0]);
    #pragma unroll
    for (int j = 0; j < 12; ++j) {
      #pragma unroll
      for (int kc = 0; kc < 8; ++kc) {
        const int g = j * 8 + kc;
        if (g < 92) { WAITV3; } else if (g == 92) { WAITV0; }
        s16x8 bf_ = *(const s16x8*)&wbuf[w][g & 7][(size_t)lane * 8];
        s16x8 af_;
        if (j < 6) af_ = *(const s16x8*)&h0b[col & 3][kc * 32 + kg * 8];
        else       af_ = *(const s16x8*)&h1b[col & 3][kc * 32 + kg * 8];
        acc2[j] = __builtin_amdgcn_mfma_f32_16x16x32_bf16(af_, bf_, acc2[j], 0, 0, 0);
        if (g + 4 < 96) {
          const int gn = g + 4, jn = gn >> 3, kn = gn & 7;
          const unsigned short* wb = (jn < 6) ? w_ih1 : w_hh1;
          const unsigned int of = (jn < 6) ? off6[jn] : off6[jn - 6];
          gld_lds16(wb + of + kn * 32, &wbuf[w][gn & 7][0]);
        }
      }
    }
    if (lane < 16) {
      #pragma unroll
      for (int i = 0; i < 4; ++i) {
        #pragma unroll
        for (int sub = 0; sub < 2; ++sub) {
          int f = w * 32 + sub * 16 + col;
          float r = sigmoidf_(acc2[sub][i] + acc2[6 + sub][i]);
          float z = sigmoidf_(acc2[2 + sub][i] + acc2[8 + sub][i]);
          float n = tanhf_(acc2[4 + sub][i] + r * acc2[10 + sub][i]);
          float hn = (1.0f - z) * n + z * h1f[i][f];
          h1f[i][f] = hn;
          unsigned short hb = f2b(hn);
          h1b[i][f] = hb;
          h1_all[((size_t)(b0 + i) * T_ + t) * 256 + f] = hb;
        }
      }
    }
    __syncthreads();
  }
}

// ---------------- Phase C ----------------
// C1: q_all = (h1_all @ Wq^T + bq) * 0.125   (bf16)
__global__ __launch_bounds__(256) void q_gemm(
    const unsigned short* __restrict__ h1_all,
    const unsigned short* __restrict__ w_q, const float* __restrict__ bq,
    unsigned short* __restrict__ q_all)
{
  __shared__ __align__(16) unsigned short A[64][264];
  const int tid = threadIdx.x;
  const int m0 = blockIdx.x * 64;
  #pragma unroll
  for (int p = 0; p < 8; ++p) {
    int idx = p * 256 + tid;
    int row = idx >> 5, c8 = idx & 31;
    *(uint4*)&A[row][c8 * 8] = *(const uint4*)&h1_all[(size_t)(m0 + row) * 256 + c8 * 8];
  }
  __syncthreads();
  const int wv = tid >> 6, lane = tid & 63;
  const int col = lane & 15, kg = lane >> 4;
  f32x4 acc[16];
  #pragma unroll
  for (int ct = 0; ct < 16; ++ct) {
    float bz = bq[ct * 16 + col];
    acc[ct][0]=bz; acc[ct][1]=bz; acc[ct][2]=bz; acc[ct][3]=bz;
  }
  #pragma unroll
  for (int kc = 0; kc < 8; ++kc) {
    s16x8 af = *(const s16x8*)&A[wv * 16 + col][kc * 32 + kg * 8];
    #pragma unroll
    for (int ct = 0; ct < 16; ++ct) {
      s16x8 bf = *(const s16x8*)&w_q[(size_t)(ct * 16 + col) * 256 + kc * 32 + kg * 8];
      acc[ct] = __builtin_amdgcn_mfma_f32_16x16x32_bf16(af, bf, acc[ct], 0, 0, 0);
    }
  }
  const int r0 = m0 + wv * 16 + kg * 4;
  #pragma unroll
  for (int ct = 0; ct < 16; ++ct) {
    int j = ct * 16 + col;
    #pragma unroll
    for (int i = 0; i < 4; ++i)
      q_all[(size_t)(r0 + i) * 256 + j] = f2b(acc[ct][i] * 0.125f);
  }
}

// C2: attention per (b): scores = q.k, softmax(+mask), ctx = a.v  -> ctx_all
__global__ __launch_bounds__(256) void attn_kernel(
    const unsigned short* __restrict__ q_all,
    const unsigned short* __restrict__ k_all,
    const unsigned short* __restrict__ v_all,
    const unsigned char* __restrict__ amask,
    unsigned short* __restrict__ ctx_all)
{
  __shared__ __align__(16) unsigned short qh[64][72];
  __shared__ __align__(16) unsigned short kh[128][72];
  __shared__ __align__(16) unsigned short vT[64][136];
  __shared__ __align__(16) unsigned short P[64][136];
  const int b = blockIdx.x;
  const int tid = threadIdx.x;
  const int wv = tid >> 6, lane = tid & 63;
  const int col = lane & 15, kg = lane >> 4;
  bool mk[8];
  #pragma unroll
  for (int nt = 0; nt < 8; ++nt) mk[nt] = amask[(size_t)b * 128 + nt * 16 + col] != 0;

  #pragma unroll 1
  for (int h = 0; h < 4; ++h) {
    #pragma unroll
    for (int p = 0; p < 2; ++p) {
      int idx = p * 256 + tid, row = idx >> 3, c8 = idx & 7;
      *(uint4*)&qh[row][c8 * 8] = *(const uint4*)&q_all[((size_t)b * 64 + row) * 256 + h * 64 + c8 * 8];
    }
    #pragma unroll
    for (int p = 0; p < 4; ++p) {
      int idx = p * 256 + tid, row = idx >> 3, c8 = idx & 7;
      *(uint4*)&kh[row][c8 * 8] = *(const uint4*)&k_all[((size_t)b * 128 + row) * 256 + h * 64 + c8 * 8];
    }
    #pragma unroll
    for (int rep = 0; rep < 32; ++rep) {
      int e = rep * 256 + tid;
      int n = e >> 6, d = e & 63;
      vT[d][n] = v_all[((size_t)b * 128 + n) * 256 + h * 64 + d];
    }
    __syncthreads();

    s16x8 aq0 = *(const s16x8*)&qh[wv * 16 + col][kg * 8];
    s16x8 aq1 = *(const s16x8*)&qh[wv * 16 + col][32 + kg * 8];
    f32x4 s[8];
    #pragma unroll
    for (int nt = 0; nt < 8; ++nt) {
      f32x4 z = {0.f, 0.f, 0.f, 0.f};
      s16x8 bk0 = *(const s16x8*)&kh[nt * 16 + col][kg * 8];
      s16x8 bk1 = *(const s16x8*)&kh[nt * 16 + col][32 + kg * 8];
      z = __builtin_amdgcn_mfma_f32_16x16x32_bf16(aq0, bk0, z, 0, 0, 0);
      z = __builtin_amdgcn_mfma_f32_16x16x32_bf16(aq1, bk1, z, 0, 0, 0);
      s[nt] = z;
    }
    #pragma unroll
    for (int nt = 0; nt < 8; ++nt)
      if (mk[nt]) { s[nt][0] = -1e9f; s[nt][1] = -1e9f; s[nt][2] = -1e9f; s[nt][3] = -1e9f; }
    f32x4 mx = s[0];
    #pragma unroll
    for (int nt = 1; nt < 8; ++nt)
      #pragma unroll
      for (int i = 0; i < 4; ++i) mx[i] = fmaxf(mx[i], s[nt][i]);
    #pragma unroll
    for (int i = 0; i < 4; ++i) {
      float m = mx[i];
      m = fmaxf(m, __shfl_xor(m, 1)); m = fmaxf(m, __shfl_xor(m, 2));
      m = fmaxf(m, __shfl_xor(m, 4)); m = fmaxf(m, __shfl_xor(m, 8));
      mx[i] = m;
    }
    f32x4 sm = {0.f, 0.f, 0.f, 0.f};
    #pragma unroll
    for (int nt = 0; nt < 8; ++nt)
      #pragma unroll
      for (int i = 0; i < 4; ++i) { s[nt][i] = __expf(s[nt][i] - mx[i]); sm[i] += s[nt][i]; }
    #pragma unroll
    for (int i = 0; i < 4; ++i) {
      float t2 = sm[i];
      t2 += __shfl_xor(t2, 1); t2 += __shfl_xor(t2, 2);
      t2 += __shfl_xor(t2, 4); t2 += __shfl_xor(t2, 8);
      sm[i] = 1.0f / t2;
    }
    #pragma unroll
    for (int nt = 0; nt < 8; ++nt)
      #pragma unroll
      for (int i = 0; i < 4; ++i)
        P[wv * 16 + kg * 4 + i][nt * 16 + col] = f2b(s[nt][i] * sm[i]);
    __syncthreads();

    f32x4 c4[4];
    #pragma unroll
    for (int dt = 0; dt < 4; ++dt) { c4[dt][0]=0.f; c4[dt][1]=0.f; c4[dt][2]=0.f; c4[dt][3]=0.f; }
    #pragma unroll
    for (int kc = 0; kc < 4; ++kc) {
      s16x8 ap = *(const s16x8*)&P[wv * 16 + col][kc * 32 + kg * 8];
      #pragma unroll
      for (int dt = 0; dt < 4; ++dt) {
        s16x8 bv_ = *(const s16x8*)&vT[dt * 16 + col][kc * 32 + kg * 8];
        c4[dt] = __builtin_amdgcn_mfma_f32_16x16x32_bf16(ap, bv_, c4[dt], 0, 0, 0);
      }
    }
    #pragma unroll
    for (int dt = 0; dt < 4; ++dt) {
      int d = h * 64 + dt * 16 + col;
      #pragma unroll
      for (int i = 0; i < 4; ++i)
        ctx_all[((size_t)b * 64 + wv * 16 + kg * 4 + i) * 256 + d] = f2b(c4[dt][i]);
    }
    __syncthreads();
  }
}

// C3: o = ctx@Wo^T+bo; comb = relu([h1,o]@Wc^T+bc); w1 = relu(comb@W1^T+b1);
//     out = sigmoid(w1.W2 + b2)
__global__ __launch_bounds__(256) void out_chain(
    const unsigned short* __restrict__ h1_all,
    const unsigned short* __restrict__ ctx_all,
    const unsigned short* __restrict__ w_o, const float* __restrict__ bo,
    const unsigned short* __restrict__ w_c, const float* __restrict__ bc,
    const unsigned short* __restrict__ w_1, const float* __restrict__ b1,
    const float* __restrict__ W2, const float* __restrict__ b2,
    float* __restrict__ out)
{
  __shared__ __align__(16) unsigned short BufA[64][264];
  __shared__ __align__(16) unsigned short BufB[64][264];
  const int b = blockIdx.x;
  const int tid = threadIdx.x;
  const int wv = tid >> 6, lane = tid & 63;
  const int col = lane & 15, kg = lane >> 4;
  const size_t mbase = (size_t)b * 64;
  #pragma unroll
  for (int p = 0; p < 8; ++p) {
    int idx = p * 256 + tid, row = idx >> 5, c8 = idx & 31;
    *(uint4*)&BufA[row][c8 * 8] = *(const uint4*)&h1_all[(mbase + row) * 256 + c8 * 8];
    *(uint4*)&BufB[row][c8 * 8] = *(const uint4*)&ctx_all[(mbase + row) * 256 + c8 * 8];
  }
  __syncthreads();
  f32x4 acc[16];

  // step1: o = ctx @ Wo^T + bo
  #pragma unroll
  for (int ct = 0; ct < 16; ++ct) { float bz = bo[ct*16+col]; acc[ct][0]=bz; acc[ct][1]=bz; acc[ct][2]=bz; acc[ct][3]=bz; }
  #pragma unroll
  for (int kc = 0; kc < 8; ++kc) {
    s16x8 af = *(const s16x8*)&BufB[wv * 16 + col][kc * 32 + kg * 8];
    #pragma unroll
    for (int ct = 0; ct < 16; ++ct) {
      s16x8 bf = *(const s16x8*)&w_o[(size_t)(ct * 16 + col) * 256 + kc * 32 + kg * 8];
      acc[ct] = __builtin_amdgcn_mfma_f32_16x16x32_bf16(af, bf, acc[ct], 0, 0, 0);
    }
  }
  __syncthreads();
  #pragma unroll
  for (int ct = 0; ct < 16; ++ct)
    #pragma unroll
    for (int i = 0; i < 4; ++i)
      BufB[wv * 16 + kg * 4 + i][ct * 16 + col] = f2b(acc[ct][i]);
  __syncthreads();

  // step2: comb = relu(h1@Wc[:,:256]^T + o@Wc[:,256:]^T + bc)
  #pragma unroll
  for (int ct = 0; ct < 16; ++ct) { float bz = bc[ct*16+col]; acc[ct][0]=bz; acc[ct][1]=bz; acc[ct][2]=bz; acc[ct][3]=bz; }
  #pragma unroll
  for (int kc = 0; kc < 16; ++kc) {
    s16x8 af;
    if (kc < 8) af = *(const s16x8*)&BufA[wv * 16 + col][kc * 32 + kg * 8];
    else        af = *(const s16x8*)&BufB[wv * 16 + col][(kc - 8) * 32 + kg * 8];
    #pragma unroll
    for (int ct = 0; ct < 16; ++ct) {
      s16x8 bf = *(const s16x8*)&w_c[(size_t)(ct * 16 + col) * 512 + kc * 32 + kg * 8];
      acc[ct] = __builtin_amdgcn_mfma_f32_16x16x32_bf16(af, bf, acc[ct], 0, 0, 0);
    }
  }
  __syncthreads();
  #pragma unroll
  for (int ct = 0; ct < 16; ++ct)
    #pragma unroll
    for (int i = 0; i < 4; ++i)
      BufB[wv * 16 + kg * 4 + i][ct * 16 + col] = f2b(fmaxf(acc[ct][i], 0.0f));
  __syncthreads();

  // step3: w1 = relu(comb @ W1^T + b1)
  #pragma unroll
  for (int ct = 0; ct < 16; ++ct) { float bz = b1[ct*16+col]; acc[ct][0]=bz; acc[ct][1]=bz; acc[ct][2]=bz; acc[ct][3]=bz; }
  #pragma unroll
  for (int kc = 0; kc < 8; ++kc) {
    s16x8 af = *(const s16x8*)&BufB[wv * 16 + col][kc * 32 + kg * 8];
    #pragma unroll
    for (int ct = 0; ct < 16; ++ct) {
      s16x8 bf = *(const s16x8*)&w_1[(size_t)(ct * 16 + col) * 256 + kc * 32 + kg * 8];
      acc[ct] = __builtin_amdgcn_mfma_f32_16x16x32_bf16(af, bf, acc[ct], 0, 0, 0);
    }
  }
  __syncthreads();
  #pragma unroll
  for (int ct = 0; ct < 16; ++ct)
    #pragma unroll
    for (int i = 0; i < 4; ++i)
      BufA[wv * 16 + kg * 4 + i][ct * 16 + col] = f2b(fmaxf(acc[ct][i], 0.0f));
  __syncthreads();

  // step4: out = sigmoid(w1 . W2 + b2)
  {
    int r = tid >> 2, qq = tid & 3;
    float a = 0.0f;
    #pragma unroll
    for (int i2 = 0; i2 < 64; ++i2) {
      int k = qq * 64 + i2;
      a += b2f(BufA[r][k]) * W2[k];
    }
    a += __shfl_xor(a, 1); a += __shfl_xor(a, 2);
    if (qq == 0) out[mbase + r] = sigmoidf_(a + b2[0]);
  }
}

extern "C" void kernel_launch(void* const* d_in, const int* in_sizes, int n_in,
                              void* d_out, int out_size, void* d_ws, size_t ws_size,
                              hipStream_t stream)
{
  (void)in_sizes; (void)n_in; (void)out_size;
  const float* x    = (const float*)d_in[0];
  const float* phn  = (const float*)d_in[1];
  const float* h0i  = (const float*)d_in[2];
  const float* W_in = (const float*)d_in[3];
  const float* b_in = (const float*)d_in[4];
  const float* Wih0 = (const float*)d_in[5];
  const float* Whh0 = (const float*)d_in[6];
  const float* bih0 = (const float*)d_in[7];
  const float* bhh0 = (const float*)d_in[8];
  const float* Wih1 = (const float*)d_in[9];
  const float* Whh1 = (const float*)d_in[10];
  const float* bih1 = (const float*)d_in[11];
  const float* bhh1 = (const float*)d_in[12];
  const float* Wq = (const float*)d_in[13];
  const float* Wk = (const float*)d_in[14];
  const float* Wv = (const float*)d_in[15];
  const float* bq = (const float*)d_in[16];
  const float* bk = (const float*)d_in[17];
  const float* bv = (const float*)d_in[18];
  const float* Wo = (const float*)d_in[19];
  const float* bo = (const float*)d_in[20];
  const float* Wc = (const float*)d_in[21];
  const float* bc = (const float*)d_in[22];
  const float* W1 = (const float*)d_in[23];
  const float* b1 = (const float*)d_in[24];
  const float* W2 = (const float*)d_in[25];
  const float* b2 = (const float*)d_in[26];
  const unsigned char* amask = (const unsigned char*)d_in[27];
  float* out = (float*)d_out;

  unsigned short* ws = (unsigned short*)d_ws;
  size_t off = 0;
  unsigned short* w_hh0 = ws + off; off += 196608;
  unsigned short* w_ih1 = ws + off; off += 196608;
  unsigned short* w_hh1 = ws + off; off += 196608;
  unsigned short* w_q   = ws + off; off += 65536;
  unsigned short* w_o   = ws + off; off += 65536;
  unsigned short* w_c   = ws + off; off += 131072;
  unsigned short* w_1   = ws + off; off += 65536;
  unsigned short* k_all = ws + off; off += (size_t)B_ * N_ * 256;
  unsigned short* v_all = ws + off; off += (size_t)B_ * N_ * 256;
  unsigned short* h1_all = ws + off; off += (size_t)B_ * T_ * 256;
  unsigned short* bigR  = ws + off; off += (size_t)B_ * T_ * 768;   // gi0, later q/ctx
  unsigned short* gi0   = bigR;
  unsigned short* q_all = bigR;                                     // alias after seq2
  unsigned short* ctx_all = bigR + (size_t)B_ * T_ * 256;
  if (ws_size < off * sizeof(unsigned short)) return;

  hipLaunchKernelGGL(cvt_bf16, dim3(384), dim3(512), 0, stream, Whh0, w_hh0, 196608);
  hipLaunchKernelGGL(cvt_bf16, dim3(384), dim3(512), 0, stream, Wih1, w_ih1, 196608);
  hipLaunchKernelGGL(cvt_bf16, dim3(384), dim3(512), 0, stream, Whh1, w_hh1, 196608);
  hipLaunchKernelGGL(cvt_bf16, dim3(128), dim3(512), 0, stream, Wq, w_q, 65536);
  hipLaunchKernelGGL(cvt_bf16, dim3(128), dim3(512), 0, stream, Wo, w_o, 65536);
  hipLaunchKernelGGL(cvt_bf16, dim3(256), dim3(512), 0, stream, Wc, w_c, 131072);
  hipLaunchKernelGGL(cvt_bf16, dim3(128), dim3(512), 0, stream, W1, w_1, 65536);

  hipLaunchKernelGGL(kv_gemm, dim3(2048, 2), dim3(256), 0, stream,
                     phn, Wk, Wv, bk, bv, k_all, v_all);
  hipLaunchKernelGGL(gi0_gemm, dim3(1024, 3), dim3(256), 0, stream,
                     x, W_in, b_in, Wih0, bih0, gi0);
  hipLaunchKernelGGL(seq2_kernel, dim3(256), dim3(512), 0, stream,
                     gi0, h0i, w_hh0, bhh0, w_ih1, bih1, w_hh1, bhh1, h1_all);
  hipLaunchKernelGGL(q_gemm, dim3(1024), dim3(256), 0, stream,
                     h1_all, w_q, bq, q_all);
  hipLaunchKernelGGL(attn_kernel, dim3(1024), dim3(256), 0, stream,
                     q_all, k_all, v_all, amask, ctx_all);
  hipLaunchKernelGGL(out_chain, dim3(1024), dim3(256), 0, stream,
                     h1_all, ctx_all, w_o, bo, w_c, bc, w_1, b1, W2, b2, out);
}